// Round 9
// baseline (227.345 us; speedup 1.0000x reference)
//
#include <hip/hip_runtime.h>
#include <math.h>

#define NEG_BIG  (-1e30f)
#define NEG_H16  (-60000.0f)   // "empty" marker safe in fp16

typedef _Float16 half8  __attribute__((ext_vector_type(8)));
typedef _Float16 half2v __attribute__((ext_vector_type(2)));
typedef float    floatx4 __attribute__((ext_vector_type(4)));

// ---------------------------------------------------------------------------
// Kernel 0 (fused aux), 113 blocks — verbatim R4/R5/R7:
//   blocks 0..47  : feat fp32->fp16 (A-operand layout [c][p])
//   block  48     : folded constants PA/PB/PS
//   blocks 49..112: 64 LC tables [p][(R-1)*4+vcb], vcb=(X>>4)&3, fp16 ln(mult)
// ---------------------------------------------------------------------------
__global__ __launch_bounds__(256) void setup_all(
    const float* __restrict__ feat, const float* __restrict__ guide,
    const float* __restrict__ sx_raw, const float* __restrict__ sy_raw,
    const float* __restrict__ th_raw, const float* __restrict__ sr_raw,
    _Float16* __restrict__ feat16, float4* __restrict__ PA,
    float4* __restrict__ PB, float* __restrict__ PS,
    _Float16* __restrict__ LCtab)
{
    const int b = blockIdx.x, t = threadIdx.x;
    if (b < 48) {
        int i = (b*256 + t)*8;
        float4 f0 = *(const float4*)(feat + i);
        float4 f1 = *(const float4*)(feat + i + 4);
        half8 h;
        h[0]=(_Float16)f0.x; h[1]=(_Float16)f0.y; h[2]=(_Float16)f0.z; h[3]=(_Float16)f0.w;
        h[4]=(_Float16)f1.x; h[5]=(_Float16)f1.y; h[6]=(_Float16)f1.z; h[7]=(_Float16)f1.w;
        *(half8*)(feat16 + i) = h;
        return;
    }
    if (b == 48) {
        float sx = expf(sx_raw[t]);
        float sy = expf(sy_raw[t]);
        float th = 3.14159265358979323846f * tanhf(th_raw[t]);
        float sr = expf(sr_raw[t]);
        float sxg = fmaxf(sx, 1e-6f), syg = fmaxf(sy, 1e-6f), srg = fmaxf(sr, 1e-6f);
        float iA = 1.f / (2.f*sxg*sxg + 1e-8f);
        float iB = 1.f / (2.f*syg*syg + 1e-8f);
        float iC = 1.f / (2.f*srg*srg + 1e-8f);
        float ct = cosf(th), st = sinf(th);
        float A2 = iA*ct*ct + iB*st*st;
        float B2 = 2.f*ct*st*(iA - iB);
        float C2 = iA*st*st + iB*ct*ct;
        PA[t] = make_float4(-A2, -B2, -C2, -iC);
        int i = t >> 4, j = t & 15;
        int y0 = 16*i + 7, x0 = 16*j + 7;   // bilinear 256->16 == 2x2 average
        float g[3];
#pragma unroll
        for (int c = 0; c < 3; ++c) {
            const float* gp = guide + c*65536;
            g[c] = 0.25f*(gp[y0*256 + x0]     + gp[y0*256 + x0 + 1] +
                          gp[(y0+1)*256 + x0] + gp[(y0+1)*256 + x0 + 1]);
        }
        PB[t] = make_float4(2.f*iC*g[0], 2.f*iC*g[1], 2.f*iC*g[2],
                            -iC*(g[0]*g[0] + g[1]*g[1] + g[2]*g[2]));
        PS[t] = fmaxf(sx, sy);
        return;
    }
    // ---- LC tables (same counting math as the verified round-1 build) ----
    const int tb  = b - 49;           // 0..63
    const int uc  = tb >> 2;          // 0..15
    const int vc0 = (tb & 3) << 2;    // X0>>4 of the 64-px strip
    const int Pu  = t >> 4;
    const int colb = t & 15;
    int ylo = (Pu == 0)  ? -8 : (Pu - uc);
    int yhi = (Pu == 15) ?  8 : (Pu - uc);
    ylo = max(ylo, -8); yhi = min(yhi, 8);
    _Float16* dst = LCtab + (size_t)tb * 8192;
#pragma unroll
    for (int h = 0; h < 2; ++h) {
        const int col32 = colb + h*16;          // (R-1)*4 + vcb
        const int Rt = (col32 >> 2) + 1;
        const int vc = vc0 + (col32 & 3);
        const int R2 = Rt * Rt;
        int cnt[16];
#pragma unroll
        for (int Pv = 1; Pv < 15; ++Pv) {
            int d = Pv - vc;
            int lim = R2 - d*d;
            int c = 0;
            if (lim >= 0 && ylo <= yhi) {
                int s = (int)sqrtf((float)lim);   // exact for ints <= 64
                c = max(0, min(yhi, s) - max(ylo, -s) + 1);
            }
            cnt[Pv] = c;
        }
        cnt[0] = 0;
        if (-vc >= -8) {
            for (int dY = ylo; dY <= yhi; ++dY) {
                int lim = R2 - dY*dY;
                if (lim >= 0) {
                    int r = (int)sqrtf((float)lim);
                    cnt[0] += max(0, min(-vc, r) + r + 1);
                }
            }
        }
        cnt[15] = 0;
        if (15 - vc <= 8) {
            for (int dY = ylo; dY <= yhi; ++dY) {
                int lim = R2 - dY*dY;
                if (lim >= 0) {
                    int r = (int)sqrtf((float)lim);
                    cnt[15] += max(0, r - max(15 - vc, -r) + 1);
                }
            }
        }
#pragma unroll
        for (int Pv = 0; Pv < 16; ++Pv)
            dst[(Pu*16 + Pv)*32 + col32] = (_Float16)
                ((cnt[Pv] > 0) ? __logf((float)cnt[Pv]) : NEG_H16);
    }
}

// ---------------------------------------------------------------------------
// Kernel A: weights + inverse denominator — verbatim R5 (harness-verified).
// Computes Wb (XOR-swizzled fp16 weights) + den, dumps Wb byte-linear to
// global W[px][512B] (streaming 32 KB per block) + invden[px].
// ---------------------------------------------------------------------------
__global__ __launch_bounds__(1024) void jbu_wden(
    const float* __restrict__ guide, const float4* __restrict__ PA,
    const float4* __restrict__ PB, const float* __restrict__ PS,
    const _Float16* __restrict__ LCtab,
    _Float16* __restrict__ Wg, float* __restrict__ invden)
{
    __shared__ __align__(16) _Float16 Wb[64][256];  // 32 KB, row=pixel, swizzled
    __shared__ float redM[16][64];                  // per-wave max partials
    __shared__ float redD[16][64];                  // per-wave den partials

    const int t  = threadIdx.x;
    const int q  = t & 63;                       // pixel within strip
    const int wv = t >> 6;                       // 0..15 == LR row Pu
    const int grpu = __builtin_amdgcn_readfirstlane(wv);

    const int n   = blockIdx.x;
    const int Y   = n >> 2;
    const int X0  = (n & 3) << 6;
    const int X   = X0 + q;
    const float Yf = (float)Y, Xf = (float)X;
    const int uc   = Y >> 4;                     // == clip(round(u),0,15) exactly

    // ---- Per-pixel R from bilinear upsample of max(sx,sy) ----
    float u = (Yf + 0.5f)*0.0625f - 0.5f;
    float v = (Xf + 0.5f)*0.0625f - 0.5f;
    float ysc = fmaxf(u, 0.f), xsc = fmaxf(v, 0.f);
    int y0 = (int)ysc, x0 = (int)xsc;
    int y1 = min(y0 + 1, 15), x1 = min(x0 + 1, 15);
    float wy = ysc - (float)y0, wx = xsc - (float)x0;
    float s00 = PS[y0*16 + x0], s01 = PS[y0*16 + x1];
    float s10 = PS[y1*16 + x0], s11 = PS[y1*16 + x1];
    float sig = (1.f - wy)*((1.f - wx)*s00 + wx*s01)
              +        wy *((1.f - wx)*s10 + wx*s11);
    float Rf = fminf(fmaxf(ceilf(2.f*sig), 1.f), 8.f);
    const int colq = ((int)Rf - 1)*4 + (q >> 4);   // vcb = (X>>4)&3 == q>>4

    const float g0 = guide[          (Y << 8) + X];
    const float g1 = guide[ 65536 + ((Y << 8) + X)];
    const float g2 = guide[131072 + ((Y << 8) + X)];
    const float g2s = g0*g0 + g1*g1 + g2*g2;

    const _Float16* Lb = LCtab + (size_t)(uc*4 + (X0 >> 6))*8192 + colq;

    // ---- Phase 1: lw = ln(cnt) + folded 7-FMA chain (one LR row/wave) ----
    const int pbase = grpu << 4;
    const float dy  = Yf - (16.f*(float)grpu + 7.5f);
    const float dy2 = dy*dy;
    float lw[16];
    float mloc = NEG_BIG;
#pragma unroll
    for (int col = 0; col < 16; ++col) {
        int p = pbase + col;
        float dx = Xf - (16.f*(float)col + 7.5f);
        float4 A = PA[p];           // wave-uniform address -> s_load
        float4 B = PB[p];
        float w = fmaf(B.x, g0, B.w);
        w = fmaf(B.y, g1, w);
        w = fmaf(B.z, g2, w);
        w = fmaf(A.w, g2s, w);
        w = fmaf(A.x, dx*dx, w);
        w = fmaf(A.y, dx*dy, w);
        w = fmaf(A.z, dy2, w);
        w += (float)Lb[p*32];
        lw[col] = w;
        mloc = fmaxf(mloc, w);
    }
    redM[wv][q] = mloc;
    __syncthreads();   // B2
    float m = redM[0][q];
#pragma unroll
    for (int k = 1; k < 16; ++k) m = fmaxf(m, redM[k][q]);

    // ---- Phase 2: exp, fp16 round, paired swizzled LDS stores, den ----
    float dloc = 0.f;
#pragma unroll
    for (int col = 0; col < 16; col += 2) {
        int p0 = pbase + col;
        float e0 = __expf(lw[col]     - m);   // empty entries underflow to 0
        float e1 = __expf(lw[col + 1] - m);
        half2v hh; hh[0] = (_Float16)e0; hh[1] = (_Float16)e1;
        int chunk = ((p0 >> 3) ^ q) & 31;     // 16B-chunk XOR swizzle
        *(half2v*)&Wb[q][chunk*8 + (p0 & 7)] = hh;
        dloc += (float)hh[0] + (float)hh[1];  // den consistent with fp16 weights
    }
    redD[wv][q] = dloc;
    __syncthreads();   // B3: publishes Wb + redD

    // ---- invden (64 pixels, one thread each) ----
    if (t < 64) {
        float den = 0.f;
#pragma unroll
        for (int k = 0; k < 16; ++k) den += redD[k][t];
        invden[(Y << 8) + X0 + t] = 1.f / fmaxf(den, 1e-8f);
    }

    // ---- W dump: byte-linear copy Wb -> Wg (32 KB contiguous per block) ----
    {
        const float4* src = (const float4*)((const char*)Wb + t*32);
        float4* dst = (float4*)((char*)Wg
                        + ((size_t)(Y << 8) + (size_t)X0)*512 + (size_t)t*32);
        dst[0] = src[0];
        dst[1] = src[1];
    }
}

// ---------------------------------------------------------------------------
// Kernel B: GEMM with 2 KB-per-channel write bursts (the burst-size probe).
// 256 blocks x 1024 threads. Block b: px-span = (b & 127)*512 (one row PAIR),
// channel half = (b >> 7)*192. Siblings b, b+128 differ by 128 ≡ 0 (mod 8)
// -> same XCD -> shared L2 copy of the 256 KB W slice.
// 16 waves = px quarters (32 px each); wave tile 96ch x 32px = acc[6][2];
// 2 slabs of 96 ch. B-frags from global W with the R5-verified chunk-XOR
// (bit-identical bytes to the fused kernel's LDS reads).
// Epilogue per slab: 3 episodes {stage 32ch x 512px in LDS (stride 516,
// <=2-way), barrier, each wave nt-stores 2 channels x 2 KB contiguous}.
// nt stores (ext_vector ptr — HIP float4* rejected by the builtin) also
// keep the out-stream from evicting the W slice.
// ---------------------------------------------------------------------------
__global__ __launch_bounds__(1024) void jbu_gemm2(
    const _Float16* __restrict__ feat16, const _Float16* __restrict__ Wg,
    const float* __restrict__ invden, float* __restrict__ out)
{
    __shared__ float S[32][516];                 // 66 KB staging

    const int t    = threadIdx.x;
    const int lane = t & 63;
    const int wv   = t >> 6;     // 0..15 pixel quarter
    const int mrow = lane & 15;
    const int quad = lane >> 4;

    const int b     = blockIdx.x;
    const int span  = b & 127;           // row pair
    const int chalf = b >> 7;            // 0..1 -> channels chalf*192 ..
    const int pix0  = span << 9;         // 512 px

    // per-lane W rows + invden (hoisted; identical across slabs)
    const int pxl0 = wv*32 + mrow;
    const _Float16* wr0 = Wg + (((size_t)pix0 + pxl0) << 8);
    const _Float16* wr1 = wr0 + (16 << 8);
    const int cm0 = mrow;                // (pix & 31) for nt=0
    const int cm1 = 16 + mrow;           // (pix & 31) for nt=1
    const float id0 = invden[pix0 + pxl0];
    const float id1 = invden[pix0 + pxl0 + 16];

#pragma unroll
    for (int s = 0; s < 2; ++s) {
        const int c0s = chalf*192 + s*96;
        floatx4 acc[6][2] = {};
        const _Float16* fbase = feat16 + (c0s + mrow)*256 + quad*8;

#pragma unroll
        for (int ks = 0; ks < 8; ++ks) {
            half8 a[6];
#pragma unroll
            for (int mt = 0; mt < 6; ++mt)
                a[mt] = *(const half8*)(fbase + mt*4096 + ks*32);
            half8 b0 = *(const half8*)(wr0 + (((ks*4 + quad) ^ cm0) & 31)*8);
            half8 b1 = *(const half8*)(wr1 + (((ks*4 + quad) ^ cm1) & 31)*8);
#pragma unroll
            for (int mt = 0; mt < 6; ++mt) {
                acc[mt][0] = __builtin_amdgcn_mfma_f32_16x16x32_f16(
                    a[mt], b0, acc[mt][0], 0, 0, 0);
                acc[mt][1] = __builtin_amdgcn_mfma_f32_16x16x32_f16(
                    a[mt], b1, acc[mt][1], 0, 0, 0);
            }
        }

        // ---- Epilogue: 3 episodes of 32 channels ----
#pragma unroll
        for (int e = 0; e < 3; ++e) {
            __syncthreads();             // S free (previous episode's reads done)
#pragma unroll
            for (int ml = 0; ml < 2; ++ml) {
                const int mt = e*2 + ml;
#pragma unroll
                for (int rr = 0; rr < 4; ++rr) {
                    S[ml*16 + quad*4 + rr][pxl0]      = acc[mt][0][rr] * id0;
                    S[ml*16 + quad*4 + rr][pxl0 + 16] = acc[mt][1][rr] * id1;
                }
            }
            __syncthreads();             // S published
#pragma unroll
            for (int r = 0; r < 2; ++r) {
                const int row = r*16 + wv;
                const floatx4* sp = (const floatx4*)&S[row][lane*8];
                floatx4 v0 = sp[0];
                floatx4 v1 = sp[1];
                float* dp = out + (size_t)(c0s + e*32 + row)*65536
                                + pix0 + lane*8;
                __builtin_nontemporal_store(v0, (floatx4*)dp);
                __builtin_nontemporal_store(v1, (floatx4*)(dp + 4));
            }
        }
    }
}

// ---------------------------------------------------------------------------
extern "C" void kernel_launch(void* const* d_in, const int* in_sizes, int n_in,
                              void* d_out, int out_size, void* d_ws, size_t ws_size,
                              hipStream_t stream)
{
    const float* feat   = (const float*)d_in[0];   // [1,384,16,16]
    const float* guide  = (const float*)d_in[1];   // [1,3,256,256]
    const float* sx_raw = (const float*)d_in[2];   // [1,1,16,16]
    const float* sy_raw = (const float*)d_in[3];
    const float* th_raw = (const float*)d_in[4];
    const float* sr_raw = (const float*)d_in[5];
    float* out = (float*)d_out;                    // [1,384,256,256]

    char* ws = (char*)d_ws;
    _Float16* feat16 = (_Float16*)ws;                    // 192 KB @ 0
    float4*   PA     = (float4*)(ws + 196608);           // 4 KB
    float4*   PB     = (float4*)(ws + 200704);           // 4 KB
    float*    PS     = (float*)(ws + 204800);            // 1 KB
    _Float16* LCtab  = (_Float16*)(ws + 205824);         // 1 MB (64 x 16 KB)
    _Float16* Wg     = (_Float16*)(ws + 1254400);        // 32 MB [px][512B]
    float*    invden = (float*)(ws + 1254400 + 33554432);// 256 KB

    setup_all<<<113, 256, 0, stream>>>(feat, guide, sx_raw, sy_raw, th_raw,
                                       sr_raw, feat16, PA, PB, PS, LCtab);
    jbu_wden<<<1024, 1024, 0, stream>>>(guide, PA, PB, PS, LCtab, Wg, invden);
    jbu_gemm2<<<256, 1024, 0, stream>>>(feat16, Wg, invden, out);
}

// Round 10
// 206.493 us; speedup vs baseline: 1.1010x; 1.1010x over previous
//
#include <hip/hip_runtime.h>
#include <math.h>

#define NEG_BIG  (-1e30f)
#define NEG_H16  (-60000.0f)   // "empty" marker safe in fp16

typedef _Float16 half8  __attribute__((ext_vector_type(8)));
typedef _Float16 half2v __attribute__((ext_vector_type(2)));
typedef float    floatx4 __attribute__((ext_vector_type(4)));

// ---------------------------------------------------------------------------
// Kernel 0 (fused aux), 113 blocks — verbatim R4/R5/R7/R9:
//   blocks 0..47  : feat fp32->fp16 (A-operand layout [c][p])
//   block  48     : folded constants PA/PB/PS
//   blocks 49..112: 64 LC tables [p][(R-1)*4+vcb], vcb=(X>>4)&3, fp16 ln(mult)
// ---------------------------------------------------------------------------
__global__ __launch_bounds__(256) void setup_all(
    const float* __restrict__ feat, const float* __restrict__ guide,
    const float* __restrict__ sx_raw, const float* __restrict__ sy_raw,
    const float* __restrict__ th_raw, const float* __restrict__ sr_raw,
    _Float16* __restrict__ feat16, float4* __restrict__ PA,
    float4* __restrict__ PB, float* __restrict__ PS,
    _Float16* __restrict__ LCtab)
{
    const int b = blockIdx.x, t = threadIdx.x;
    if (b < 48) {
        int i = (b*256 + t)*8;
        float4 f0 = *(const float4*)(feat + i);
        float4 f1 = *(const float4*)(feat + i + 4);
        half8 h;
        h[0]=(_Float16)f0.x; h[1]=(_Float16)f0.y; h[2]=(_Float16)f0.z; h[3]=(_Float16)f0.w;
        h[4]=(_Float16)f1.x; h[5]=(_Float16)f1.y; h[6]=(_Float16)f1.z; h[7]=(_Float16)f1.w;
        *(half8*)(feat16 + i) = h;
        return;
    }
    if (b == 48) {
        float sx = expf(sx_raw[t]);
        float sy = expf(sy_raw[t]);
        float th = 3.14159265358979323846f * tanhf(th_raw[t]);
        float sr = expf(sr_raw[t]);
        float sxg = fmaxf(sx, 1e-6f), syg = fmaxf(sy, 1e-6f), srg = fmaxf(sr, 1e-6f);
        float iA = 1.f / (2.f*sxg*sxg + 1e-8f);
        float iB = 1.f / (2.f*syg*syg + 1e-8f);
        float iC = 1.f / (2.f*srg*srg + 1e-8f);
        float ct = cosf(th), st = sinf(th);
        float A2 = iA*ct*ct + iB*st*st;
        float B2 = 2.f*ct*st*(iA - iB);
        float C2 = iA*st*st + iB*ct*ct;
        PA[t] = make_float4(-A2, -B2, -C2, -iC);
        int i = t >> 4, j = t & 15;
        int y0 = 16*i + 7, x0 = 16*j + 7;   // bilinear 256->16 == 2x2 average
        float g[3];
#pragma unroll
        for (int c = 0; c < 3; ++c) {
            const float* gp = guide + c*65536;
            g[c] = 0.25f*(gp[y0*256 + x0]     + gp[y0*256 + x0 + 1] +
                          gp[(y0+1)*256 + x0] + gp[(y0+1)*256 + x0 + 1]);
        }
        PB[t] = make_float4(2.f*iC*g[0], 2.f*iC*g[1], 2.f*iC*g[2],
                            -iC*(g[0]*g[0] + g[1]*g[1] + g[2]*g[2]));
        PS[t] = fmaxf(sx, sy);
        return;
    }
    // ---- LC tables (same counting math as the verified round-1 build) ----
    const int tb  = b - 49;           // 0..63
    const int uc  = tb >> 2;          // 0..15
    const int vc0 = (tb & 3) << 2;    // X0>>4 of the 64-px strip
    const int Pu  = t >> 4;
    const int colb = t & 15;
    int ylo = (Pu == 0)  ? -8 : (Pu - uc);
    int yhi = (Pu == 15) ?  8 : (Pu - uc);
    ylo = max(ylo, -8); yhi = min(yhi, 8);
    _Float16* dst = LCtab + (size_t)tb * 8192;
#pragma unroll
    for (int h = 0; h < 2; ++h) {
        const int col32 = colb + h*16;          // (R-1)*4 + vcb
        const int Rt = (col32 >> 2) + 1;
        const int vc = vc0 + (col32 & 3);
        const int R2 = Rt * Rt;
        int cnt[16];
#pragma unroll
        for (int Pv = 1; Pv < 15; ++Pv) {
            int d = Pv - vc;
            int lim = R2 - d*d;
            int c = 0;
            if (lim >= 0 && ylo <= yhi) {
                int s = (int)sqrtf((float)lim);   // exact for ints <= 64
                c = max(0, min(yhi, s) - max(ylo, -s) + 1);
            }
            cnt[Pv] = c;
        }
        cnt[0] = 0;
        if (-vc >= -8) {
            for (int dY = ylo; dY <= yhi; ++dY) {
                int lim = R2 - dY*dY;
                if (lim >= 0) {
                    int r = (int)sqrtf((float)lim);
                    cnt[0] += max(0, min(-vc, r) + r + 1);
                }
            }
        }
        cnt[15] = 0;
        if (15 - vc <= 8) {
            for (int dY = ylo; dY <= yhi; ++dY) {
                int lim = R2 - dY*dY;
                if (lim >= 0) {
                    int r = (int)sqrtf((float)lim);
                    cnt[15] += max(0, r - max(15 - vc, -r) + 1);
                }
            }
        }
#pragma unroll
        for (int Pv = 0; Pv < 16; ++Pv)
            dst[(Pu*16 + Pv)*32 + col32] = (_Float16)
                ((cnt[Pv] > 0) ? __logf((float)cnt[Pv]) : NEG_H16);
    }
}

// ---------------------------------------------------------------------------
// Kernel A: weights + inverse denominator — verbatim R5/R9 (harness-verified).
// Computes Wb (XOR-swizzled fp16 weights) + den, dumps Wb byte-linear to
// global W[px][512B] (streaming 32 KB per block) + invden[px].
// ---------------------------------------------------------------------------
__global__ __launch_bounds__(1024) void jbu_wden(
    const float* __restrict__ guide, const float4* __restrict__ PA,
    const float4* __restrict__ PB, const float* __restrict__ PS,
    const _Float16* __restrict__ LCtab,
    _Float16* __restrict__ Wg, float* __restrict__ invden)
{
    __shared__ __align__(16) _Float16 Wb[64][256];  // 32 KB, row=pixel, swizzled
    __shared__ float redM[16][64];                  // per-wave max partials
    __shared__ float redD[16][64];                  // per-wave den partials

    const int t  = threadIdx.x;
    const int q  = t & 63;                       // pixel within strip
    const int wv = t >> 6;                       // 0..15 == LR row Pu
    const int grpu = __builtin_amdgcn_readfirstlane(wv);

    const int n   = blockIdx.x;
    const int Y   = n >> 2;
    const int X0  = (n & 3) << 6;
    const int X   = X0 + q;
    const float Yf = (float)Y, Xf = (float)X;
    const int uc   = Y >> 4;                     // == clip(round(u),0,15) exactly

    // ---- Per-pixel R from bilinear upsample of max(sx,sy) ----
    float u = (Yf + 0.5f)*0.0625f - 0.5f;
    float v = (Xf + 0.5f)*0.0625f - 0.5f;
    float ysc = fmaxf(u, 0.f), xsc = fmaxf(v, 0.f);
    int y0 = (int)ysc, x0 = (int)xsc;
    int y1 = min(y0 + 1, 15), x1 = min(x0 + 1, 15);
    float wy = ysc - (float)y0, wx = xsc - (float)x0;
    float s00 = PS[y0*16 + x0], s01 = PS[y0*16 + x1];
    float s10 = PS[y1*16 + x0], s11 = PS[y1*16 + x1];
    float sig = (1.f - wy)*((1.f - wx)*s00 + wx*s01)
              +        wy *((1.f - wx)*s10 + wx*s11);
    float Rf = fminf(fmaxf(ceilf(2.f*sig), 1.f), 8.f);
    const int colq = ((int)Rf - 1)*4 + (q >> 4);   // vcb = (X>>4)&3 == q>>4

    const float g0 = guide[          (Y << 8) + X];
    const float g1 = guide[ 65536 + ((Y << 8) + X)];
    const float g2 = guide[131072 + ((Y << 8) + X)];
    const float g2s = g0*g0 + g1*g1 + g2*g2;

    const _Float16* Lb = LCtab + (size_t)(uc*4 + (X0 >> 6))*8192 + colq;

    // ---- Phase 1: lw = ln(cnt) + folded 7-FMA chain (one LR row/wave) ----
    const int pbase = grpu << 4;
    const float dy  = Yf - (16.f*(float)grpu + 7.5f);
    const float dy2 = dy*dy;
    float lw[16];
    float mloc = NEG_BIG;
#pragma unroll
    for (int col = 0; col < 16; ++col) {
        int p = pbase + col;
        float dx = Xf - (16.f*(float)col + 7.5f);
        float4 A = PA[p];           // wave-uniform address -> s_load
        float4 B = PB[p];
        float w = fmaf(B.x, g0, B.w);
        w = fmaf(B.y, g1, w);
        w = fmaf(B.z, g2, w);
        w = fmaf(A.w, g2s, w);
        w = fmaf(A.x, dx*dx, w);
        w = fmaf(A.y, dx*dy, w);
        w = fmaf(A.z, dy2, w);
        w += (float)Lb[p*32];
        lw[col] = w;
        mloc = fmaxf(mloc, w);
    }
    redM[wv][q] = mloc;
    __syncthreads();   // B2
    float m = redM[0][q];
#pragma unroll
    for (int k = 1; k < 16; ++k) m = fmaxf(m, redM[k][q]);

    // ---- Phase 2: exp, fp16 round, paired swizzled LDS stores, den ----
    float dloc = 0.f;
#pragma unroll
    for (int col = 0; col < 16; col += 2) {
        int p0 = pbase + col;
        float e0 = __expf(lw[col]     - m);   // empty entries underflow to 0
        float e1 = __expf(lw[col + 1] - m);
        half2v hh; hh[0] = (_Float16)e0; hh[1] = (_Float16)e1;
        int chunk = ((p0 >> 3) ^ q) & 31;     // 16B-chunk XOR swizzle
        *(half2v*)&Wb[q][chunk*8 + (p0 & 7)] = hh;
        dloc += (float)hh[0] + (float)hh[1];  // den consistent with fp16 weights
    }
    redD[wv][q] = dloc;
    __syncthreads();   // B3: publishes Wb + redD

    // ---- invden (64 pixels, one thread each) ----
    if (t < 64) {
        float den = 0.f;
#pragma unroll
        for (int k = 0; k < 16; ++k) den += redD[k][t];
        invden[(Y << 8) + X0 + t] = 1.f / fmaxf(den, 1e-8f);
    }

    // ---- W dump: byte-linear copy Wb -> Wg (32 KB contiguous per block) ----
    {
        const float4* src = (const float4*)((const char*)Wb + t*32);
        float4* dst = (float4*)((char*)Wg
                        + ((size_t)(Y << 8) + (size_t)X0)*512 + (size_t)t*32);
        dst[0] = src[0];
        dst[1] = src[1];
    }
}

// ---------------------------------------------------------------------------
// Kernel B: GEMM with 2 KB-per-channel write bursts — SPILL-FREE retry of R9.
// R9 failed its tripwire: 1024-thr blocks -> 8 waves/SIMD -> 64-VGPR cap;
// acc[6][2]=48 + a[6]=24 transient > 64 -> 100 MB accumulator spill
// (WRITE 196 MB, VALUBusy 2.7%). Fix is structural: wave tile 48ch x 32px
// (acc[3][2]=24, peak live ~55 regs — the R3/R4-verified accumulator shape),
// four sequential 48-ch passes.
// 256 blocks x 1024 threads. Block b: px-span (b&127)*512 (one row pair),
// channel half (b>>7)*192. Siblings b, b+128 -> same XCD -> shared L2 W slice.
// Per pass: 16 waves (= px quarters) x 8 ks x {3 A-loads, 2 B-loads, 6 MFMA};
// B-frags from global W with the R5-verified chunk-XOR (bit-identical bytes).
// Epilogue per pass: 3 episodes {stage 16ch x 512px in 33 KB LDS, barrier,
// wave wv nt-stores channel (c0+e*16+wv): 2 KB contiguous as 2 dwordx4}.
// ---------------------------------------------------------------------------
__global__ __launch_bounds__(1024) void jbu_gemm3(
    const _Float16* __restrict__ feat16, const _Float16* __restrict__ Wg,
    const float* __restrict__ invden, float* __restrict__ out)
{
    __shared__ float S[16][516];                 // 33 KB staging

    const int t    = threadIdx.x;
    const int lane = t & 63;
    const int wv   = t >> 6;     // 0..15 pixel quarter (32 px)
    const int mrow = lane & 15;
    const int quad = lane >> 4;

    const int b     = blockIdx.x;
    const int span  = b & 127;           // row pair
    const int chalf = b >> 7;            // 0..1 -> channels chalf*192 ..
    const int pix0  = span << 9;         // 512 px

    // per-lane W rows + invden (identical across passes)
    const int pxl0 = wv*32 + mrow;
    const _Float16* wr0 = Wg + (((size_t)pix0 + pxl0) << 8);
    const _Float16* wr1 = wr0 + (16 << 8);
    const int cm0 = mrow;                // (px & 31) for nt=0
    const int cm1 = 16 + mrow;           // (px & 31) for nt=1
    const float id0 = invden[pix0 + pxl0];
    const float id1 = invden[pix0 + pxl0 + 16];

#pragma unroll
    for (int p = 0; p < 4; ++p) {
        const int c0 = chalf*192 + p*48;
        floatx4 acc[3][2] = {};
        const _Float16* fbase = feat16 + (c0 + mrow)*256 + quad*8;

#pragma unroll
        for (int ks = 0; ks < 8; ++ks) {
            half8 a[3];
#pragma unroll
            for (int mt = 0; mt < 3; ++mt)
                a[mt] = *(const half8*)(fbase + mt*4096 + ks*32);
            half8 b0 = *(const half8*)(wr0 + (((ks*4 + quad) ^ cm0) & 31)*8);
            half8 b1 = *(const half8*)(wr1 + (((ks*4 + quad) ^ cm1) & 31)*8);
#pragma unroll
            for (int mt = 0; mt < 3; ++mt) {
                acc[mt][0] = __builtin_amdgcn_mfma_f32_16x16x32_f16(
                    a[mt], b0, acc[mt][0], 0, 0, 0);
                acc[mt][1] = __builtin_amdgcn_mfma_f32_16x16x32_f16(
                    a[mt], b1, acc[mt][1], 0, 0, 0);
            }
        }

        // ---- Epilogue: 3 episodes of 16 channels; 2 KB/channel bursts ----
#pragma unroll
        for (int e = 0; e < 3; ++e) {
            __syncthreads();             // S free (previous episode's reads done)
#pragma unroll
            for (int rr = 0; rr < 4; ++rr) {
                S[quad*4 + rr][pxl0]      = acc[e][0][rr] * id0;
                S[quad*4 + rr][pxl0 + 16] = acc[e][1][rr] * id1;
            }
            __syncthreads();             // S published
            const floatx4* sp = (const floatx4*)&S[wv][lane*8];
            floatx4 v0 = sp[0];
            floatx4 v1 = sp[1];
            float* dp = out + (size_t)(c0 + e*16 + wv)*65536 + pix0 + lane*8;
            __builtin_nontemporal_store(v0, (floatx4*)dp);
            __builtin_nontemporal_store(v1, (floatx4*)(dp + 4));
        }
    }
}

// ---------------------------------------------------------------------------
extern "C" void kernel_launch(void* const* d_in, const int* in_sizes, int n_in,
                              void* d_out, int out_size, void* d_ws, size_t ws_size,
                              hipStream_t stream)
{
    const float* feat   = (const float*)d_in[0];   // [1,384,16,16]
    const float* guide  = (const float*)d_in[1];   // [1,3,256,256]
    const float* sx_raw = (const float*)d_in[2];   // [1,1,16,16]
    const float* sy_raw = (const float*)d_in[3];
    const float* th_raw = (const float*)d_in[4];
    const float* sr_raw = (const float*)d_in[5];
    float* out = (float*)d_out;                    // [1,384,256,256]

    char* ws = (char*)d_ws;
    _Float16* feat16 = (_Float16*)ws;                    // 192 KB @ 0
    float4*   PA     = (float4*)(ws + 196608);           // 4 KB
    float4*   PB     = (float4*)(ws + 200704);           // 4 KB
    float*    PS     = (float*)(ws + 204800);            // 1 KB
    _Float16* LCtab  = (_Float16*)(ws + 205824);         // 1 MB (64 x 16 KB)
    _Float16* Wg     = (_Float16*)(ws + 1254400);        // 32 MB [px][512B]
    float*    invden = (float*)(ws + 1254400 + 33554432);// 256 KB

    setup_all<<<113, 256, 0, stream>>>(feat, guide, sx_raw, sy_raw, th_raw,
                                       sr_raw, feat16, PA, PB, PS, LCtab);
    jbu_wden<<<1024, 1024, 0, stream>>>(guide, PA, PB, PS, LCtab, Wg, invden);
    jbu_gemm3<<<256, 1024, 0, stream>>>(feat16, Wg, invden, out);
}